// Round 8
// baseline (373.597 us; speedup 1.0000x reference)
//
#include <hip/hip_runtime.h>

// Sparse 3D conv (K=3, stride=2, pad=1), dense output, direct per-point scatter.
// One WAVE per point: 64 lanes = 64 output channels; <=8 posted atomics/point.
// Inputs: features [N,32] f32, W [3,3,3,32,64] f32, coors [N,4] i32 (b,z,y,x).
// Output: [B,64,64,64,64] f32 flat (memset to 0, then posted atomic adds).
// ws: [ W_t 27*64*32 f32 ]  (~221 KB)

#define CIN   32
#define COUT  64
#define OUTD  64
#define NPTS  128

// Valid (k, o) options along one axis: o = (p+1-k)/2, parity-matched, 0<=o<64.
__device__ __forceinline__ int axis_opts(int p, int* k, int* o) {
    int cnt = 0;
    const int kp = (p + 1) & 1;          // smallest parity-matching k
    const int o0 = (p + 1 - kp) >> 1;    // >= 0 always
    if (o0 < OUTD) { k[cnt] = kp; o[cnt] = o0; ++cnt; }
    if (kp == 0) {                       // k=2 shares parity with k=0
        const int o1 = o0 - 1;
        if (o1 >= 0) { k[cnt] = 2; o[cnt] = o1; ++cnt; }
    }
    return cnt;
}

// ---------- W transpose: [27][32][64] -> [27][64][32], f32 ----------
__global__ void conv_w_t(const float* __restrict__ W, float* __restrict__ wsW)
{
    const int k = blockIdx.x;            // 27 blocks
    for (int i = threadIdx.x; i < CIN * COUT; i += 256) {
        const int c = i >> 6, ch = i & 63;     // read coalesced over i
        wsW[(k << 11) + (ch << 5) + c] = W[(k << 11) + i];
    }
}

// ---------- scatter: one wave per point, posted global atomics ----------
__global__ __launch_bounds__(256) void scatter3(
    const float* __restrict__ feats, const float* __restrict__ wsW,
    const int4* __restrict__ coors, float* __restrict__ out, int N)
{
    const int ch = threadIdx.x & 63;
    const int wv = threadIdx.x >> 6;
    const int i  = blockIdx.x * 4 + wv;
    if (i >= N) return;

    const int4 c = coors[i];                         // wave-uniform
    const float4* fp = (const float4*)(feats + (size_t)i * CIN);
    float4 f[8];
    #pragma unroll
    for (int q = 0; q < 8; ++q) f[q] = fp[q];        // broadcast row, 8 loads

    int kz[2], oz[2], ky[2], oy[2], kx[2], ox[2];
    const int nz = axis_opts(c.y, kz, oz);
    const int ny = axis_opts(c.z, ky, oy);
    const int nx = axis_opts(c.w, kx, ox);

    for (int az = 0; az < nz; ++az)
    for (int ay = 0; ay < ny; ++ay)
    for (int ax = 0; ax < nx; ++ax) {
        const int kidx = (kz[az] * 3 + ky[ay]) * 3 + kx[ax];
        const float4* wp = (const float4*)(wsW + (kidx << 11) + (ch << 5));
        float s0 = 0.f, s1 = 0.f, s2 = 0.f, s3 = 0.f;    // 4 chains, 8 FMA each
        #pragma unroll
        for (int q = 0; q < 8; ++q) {
            const float4 wq = wp[q];
            const float4 fq = f[q];
            s0 += fq.x * wq.x;
            s1 += fq.y * wq.y;
            s2 += fq.z * wq.z;
            s3 += fq.w * wq.w;
        }
        const size_t flat = (((size_t)c.x * OUTD + oz[az]) * OUTD + oy[ay]) * OUTD + ox[ax];
        unsafeAtomicAdd(out + flat * COUT + ch, (s0 + s1) + (s2 + s3));  // posted
    }
}

// ---------- fallback (ws too small for even W): round-1 scatter ----------
__global__ __launch_bounds__(256, 4) void spconv_scatter(
    const float* __restrict__ feats, const float* __restrict__ Wt,
    const int* __restrict__ coors, float* __restrict__ out, int N)
{
    __shared__ float sf[NPTS][CIN];
    __shared__ int   sc[NPTS][4];
    __shared__ int   vf[NPTS];

    const int tid = threadIdx.x;
    const int ch  = tid & 63;
    const int wv  = tid >> 6;
    const int base = blockIdx.x * NPTS;
    const int npts = min(NPTS, (int)(N - base));
    if (npts <= 0) return;

    for (int i = tid; i < npts * CIN; i += 256) sf[0][i] = feats[base * CIN + i];
    for (int i = tid; i < npts * 4; i += 256) ((int*)sc)[i] = coors[base * 4 + i];
    __syncthreads();

    for (int off = 0; off < 27; ++off) {
        const int kz = off / 9, ky = (off / 3) % 3, kx = off % 3;
        if (tid < npts) {
            const int p  = tid;
            const int nz = sc[p][1] + 1 - kz;
            const int ny = sc[p][2] + 1 - ky;
            const int nx = sc[p][3] + 1 - kx;
            const int m  = nz | ny | nx;
            const int oz = nz >> 1, oy = ny >> 1, ox = nx >> 1;
            const bool v = ((m & 0x80000001) == 0) &&
                           (oz < OUTD) && (oy < OUTD) && (ox < OUTD);
            vf[p] = v ? (((sc[p][0] * OUTD + oz) * OUTD + oy) * OUTD + ox) : -1;
        }
        const float* wp = Wt + off * (CIN * COUT) + ch;
        float w[CIN];
        #pragma unroll
        for (int c = 0; c < CIN; ++c) w[c] = wp[c * COUT];
        __syncthreads();
        for (int p = wv; p < npts; p += 4) {
            const int f = vf[p];
            if (f >= 0) {
                float s = 0.f;
                #pragma unroll
                for (int c = 0; c < CIN; ++c) s += sf[p][c] * w[c];
                atomicAdd(&out[(size_t)f * COUT + ch], s);
            }
        }
        __syncthreads();
    }
}

extern "C" void kernel_launch(void* const* d_in, const int* in_sizes, int n_in,
                              void* d_out, int out_size, void* d_ws, size_t ws_size,
                              hipStream_t stream) {
    const float* feats = (const float*)d_in[0];
    const float* Wt    = (const float*)d_in[1];
    const int*   coors = (const int*)d_in[2];
    float*       out   = (float*)d_out;

    const int N = in_sizes[0] / CIN;

    hipMemsetAsync(d_out, 0, (size_t)out_size * sizeof(float), stream);

    const size_t need = 27 * CIN * COUT * sizeof(float);
    if (ws_size >= need) {
        float* wsW = (float*)d_ws;
        conv_w_t<<<27, 256, 0, stream>>>(Wt, wsW);
        scatter3<<<(N + 3) / 4, 256, 0, stream>>>(feats, wsW, (const int4*)coors, out, N);
    } else {
        spconv_scatter<<<(N + NPTS - 1) / NPTS, 256, 0, stream>>>(feats, Wt, coors, out, N);
    }
}